// Round 2
// baseline (257.255 us; speedup 1.0000x reference)
//
#include <hip/hip_runtime.h>
#include <hip/hip_bf16.h>

// One block (128 threads = 2 waves) per ray.
// T0=64 coarse intervals, TF=128 fine samples.
// Output row per ray: [image.rgb (3), depth (1), contracted xyz (3*TF)] = 388 f32.

constexpr int kT0 = 64;
constexpr int kTF = 128;

__global__ __launch_bounds__(128)
void nerf_render_kernel(const float* __restrict__ rays_o,
                        const float* __restrict__ rays_d,
                        const float* __restrict__ aabb,
                        const float* __restrict__ weights,   // [N, 64]
                        const float* __restrict__ sigmas,    // [N, 128]
                        const float* __restrict__ rgbs,      // [N, 128, 3]
                        float* __restrict__ out)             // [N, 388] f32
{
    const int ray  = blockIdx.x;
    const int tid  = threadIdx.x;      // 0..127 — one fine sample per thread
    const int lane = tid & 63;
    const int wid  = tid >> 6;

    __shared__ float s_cdf[kT0 + 1];    // 65
    __shared__ float s_zedge[kTF + 1];  // 129
    __shared__ float s_rgb[kTF * 3];    // 384
    __shared__ float s_xyz[kTF * 3];    // 384
    __shared__ float s_red[8];          // 2 waves x {r,g,b,depth}
    __shared__ float s_wavetot;         // wave-0 transmittance product

    // ---- stage rgbs row into LDS, fully coalesced ----
    const float* rgb_row = rgbs + (size_t)ray * (kTF * 3);
    #pragma unroll
    for (int k = 0; k < 3; ++k) s_rgb[tid + 128 * k] = rgb_row[tid + 128 * k];

    // ---- ray-AABB near/far (redundant per thread; cheap) ----
    const float ox = rays_o[ray * 3 + 0], oy = rays_o[ray * 3 + 1], ozr = rays_o[ray * 3 + 2];
    const float dx = rays_d[ray * 3 + 0], dy = rays_d[ray * 3 + 1], dzr = rays_d[ray * 3 + 2];
    float near, far;
    {
        const float t0x = (aabb[0] - ox) / (dx + 1e-15f);
        const float t1x = (aabb[3] - ox) / (dx + 1e-15f);
        const float t0y = (aabb[1] - oy) / (dy + 1e-15f);
        const float t1y = (aabb[4] - oy) / (dy + 1e-15f);
        const float t0z = (aabb[2] - ozr) / (dzr + 1e-15f);
        const float t1z = (aabb[5] - ozr) / (dzr + 1e-15f);
        near = fmaxf(fmaxf(fminf(t0x, t1x), fminf(t0y, t1y)), fminf(t0z, t1z));
        far  = fminf(fminf(fmaxf(t0x, t1x), fmaxf(t0y, t1y)), fmaxf(t0z, t1z));
        if (far < near) { near = 1e9f; far = 1e9f; }
        near = fmaxf(near, 0.05f);
    }
    const float range = far - near;

    // ---- CDF over coarse weights: wave-0 inclusive scan ----
    if (wid == 0) {
        float w = weights[(size_t)ray * kT0 + lane] + 0.01f;
        float scan = w;
        #pragma unroll
        for (int off = 1; off < 64; off <<= 1) {
            float v = __shfl_up(scan, off);
            if (lane >= off) scan += v;
        }
        const float total = __shfl(scan, 63);
        s_cdf[lane + 1] = fminf(scan / total, 1.0f);
        if (lane == 0) s_cdf[0] = 0.0f;
    }
    __syncthreads();

    // ---- inverse-transform sample 129 fine bin edges ----
    for (int j = tid; j <= kTF; j += 128) {
        const float u = ((float)j + 0.5f) / (float)(kTF + 1);
        // searchsorted(cdf, u, side='right') over 65 entries: binary search
        int lo = 0, hi = kT0 + 1;
        while (lo < hi) {
            const int mid = (lo + hi) >> 1;
            if (s_cdf[mid] <= u) lo = mid + 1; else hi = mid;
        }
        int below = lo - 1; below = below < 0 ? 0 : (below > kT0 ? kT0 : below);
        int above = lo;     above = above > kT0 ? kT0 : above;
        const float c0 = s_cdf[below], c1 = s_cdf[above];
        // uniform bins: bins[i] = near + range * i/64  (i/64 exact in fp32)
        const float b0 = near + range * ((float)below * (1.0f / kT0));
        const float b1 = near + range * ((float)above * (1.0f / kT0));
        const float denom = c1 - c0;
        float t = 0.0f;
        if (denom > 0.0f)
            t = fminf(fmaxf((u - c0) / fmaxf(denom, 1e-12f), 0.0f), 1.0f);
        s_zedge[j] = b0 + t * (b1 - b0);
    }
    __syncthreads();

    // ---- per-sample alpha ----
    const float ze0 = s_zedge[tid], ze1 = s_zedge[tid + 1];
    const float delta = ze1 - ze0;
    const float z = 0.5f * (ze0 + ze1);
    const float sigma = sigmas[(size_t)ray * kTF + tid];
    const float e = expf(-sigma * delta);
    const float alpha = 1.0f - e;
    const float f = (1.0f - alpha) + 1e-10f;

    // ---- transmittance: exclusive product scan across 128 threads ----
    float scan = f;
    #pragma unroll
    for (int off = 1; off < 64; off <<= 1) {
        float v = __shfl_up(scan, off);
        if (lane >= off) scan *= v;
    }
    float excl = __shfl_up(scan, 1);
    if (lane == 0) excl = 1.0f;
    if (tid == 63) s_wavetot = scan;   // wave-0 total product
    __syncthreads();
    const float trans = (wid == 0) ? excl : s_wavetot * excl;
    const float w = alpha * trans;

    // ---- image/depth reductions ----
    float vr = w * s_rgb[3 * tid + 0];
    float vg = w * s_rgb[3 * tid + 1];
    float vb = w * s_rgb[3 * tid + 2];
    float vd = w * z;
    #pragma unroll
    for (int off = 32; off >= 1; off >>= 1) {
        vr += __shfl_down(vr, off);
        vg += __shfl_down(vg, off);
        vb += __shfl_down(vb, off);
        vd += __shfl_down(vd, off);
    }
    if (lane == 0) {
        s_red[wid * 4 + 0] = vr; s_red[wid * 4 + 1] = vg;
        s_red[wid * 4 + 2] = vb; s_red[wid * 4 + 3] = vd;
    }

    // ---- contraction warp ----
    float px = ox  + dx  * z;
    float py = oy  + dy  * z;
    float pz = ozr + dzr * z;
    const float ax = fabsf(px), ay = fabsf(py), az = fabsf(pz);
    float mag; int idx;
    if (ax >= ay && ax >= az) { mag = ax; idx = 0; }
    else if (ay >= az)        { mag = ay; idx = 1; }
    else                      { mag = az; idx = 2; }
    if (mag >= 1.0f) {
        const float inv  = 1.0f / mag;
        const float smax = (2.0f - inv) * inv;   // (2 - 1/mag) / mag
        px *= (idx == 0) ? smax : inv;
        py *= (idx == 1) ? smax : inv;
        pz *= (idx == 2) ? smax : inv;
    }
    s_xyz[3 * tid + 0] = px;
    s_xyz[3 * tid + 1] = py;
    s_xyz[3 * tid + 2] = pz;
    __syncthreads();

    // ---- output: [r, g, b, depth, xyz...] as f32, coalesced ----
    float* orow = out + (size_t)ray * (4 + kTF * 3);
    if (tid == 0) {
        orow[0] = s_red[0] + s_red[4];
        orow[1] = s_red[1] + s_red[5];
        orow[2] = s_red[2] + s_red[6];
        orow[3] = s_red[3] + s_red[7];
    }
    #pragma unroll
    for (int k = 0; k < 3; ++k) {
        const int i = tid + 128 * k;
        orow[4 + i] = s_xyz[i];
    }
}

extern "C" void kernel_launch(void* const* d_in, const int* in_sizes, int n_in,
                              void* d_out, int out_size, void* d_ws, size_t ws_size,
                              hipStream_t stream) {
    const float* rays_o  = (const float*)d_in[0];
    const float* rays_d  = (const float*)d_in[1];
    const float* aabb    = (const float*)d_in[2];
    const float* weights = (const float*)d_in[3];
    const float* sigmas  = (const float*)d_in[4];
    const float* rgbs    = (const float*)d_in[5];
    float* out           = (float*)d_out;

    const int N = in_sizes[0] / 3;   // rays_o is [N,3]
    nerf_render_kernel<<<N, 128, 0, stream>>>(rays_o, rays_d, aabb, weights, sigmas, rgbs, out);
}

// Round 3
// 222.207 us; speedup vs baseline: 1.1577x; 1.1577x over previous
//
#include <hip/hip_runtime.h>

// One WAVE (64 lanes) per ray; 256-thread block = 4 independent rays.
// T0=64 coarse intervals, TF=128 fine samples; 2 fine samples per lane.
// Output row per ray: [image.rgb (3), depth (1), contracted xyz (3*TF)] = 388 f32.
//
// VALU-bound kernel (R2: VALUBusy 82%, HBM 20%). This version removes the
// per-sample binary search (interval-owner scatter from the scan lanes),
// replaces all f32 divides with v_rcp_f32, halves redundant per-ray setup,
// and drops 2 of 3 barriers + the rgb/xyz LDS round-trips.

constexpr int kT0 = 64;
constexpr int kTF = 128;
constexpr int kRaysPerBlock = 4;   // 4 waves/block

__global__ __launch_bounds__(256)
void nerf_render_kernel(const float* __restrict__ rays_o,
                        const float* __restrict__ rays_d,
                        const float* __restrict__ aabb,
                        const float* __restrict__ weights,   // [N, 64]
                        const float* __restrict__ sigmas,    // [N, 128]
                        const float* __restrict__ rgbs,      // [N, 128, 3]
                        float* __restrict__ out)             // [N, 388]
{
    const int lane = threadIdx.x & 63;
    const int wid  = threadIdx.x >> 6;
    const int ray  = blockIdx.x * kRaysPerBlock + wid;

    __shared__ float s_zedge[kRaysPerBlock][kTF + 1];   // 4 x 129

    // ---- ray-AABB near/far (rcp instead of div) ----
    const float ox = rays_o[ray * 3 + 0], oy = rays_o[ray * 3 + 1], ozr = rays_o[ray * 3 + 2];
    const float dx = rays_d[ray * 3 + 0], dy = rays_d[ray * 3 + 1], dzr = rays_d[ray * 3 + 2];
    float near, far;
    {
        const float rx = __builtin_amdgcn_rcpf(dx + 1e-15f);
        const float ry = __builtin_amdgcn_rcpf(dy + 1e-15f);
        const float rz = __builtin_amdgcn_rcpf(dzr + 1e-15f);
        const float t0x = (aabb[0] - ox) * rx, t1x = (aabb[3] - ox) * rx;
        const float t0y = (aabb[1] - oy) * ry, t1y = (aabb[4] - oy) * ry;
        const float t0z = (aabb[2] - ozr) * rz, t1z = (aabb[5] - ozr) * rz;
        near = fmaxf(fmaxf(fminf(t0x, t1x), fminf(t0y, t1y)), fminf(t0z, t1z));
        far  = fminf(fminf(fmaxf(t0x, t1x), fmaxf(t0y, t1y)), fmaxf(t0z, t1z));
        if (far < near) { near = 1e9f; far = 1e9f; }
        near = fmaxf(near, 0.05f);
    }
    const float range = far - near;

    // ---- CDF inclusive scan over coarse weights (all 64 lanes) ----
    float wgt = weights[(size_t)ray * kT0 + lane] + 0.01f;
    float scan = wgt;
    #pragma unroll
    for (int off = 1; off < 64; off <<= 1) {
        float v = __shfl_up(scan, off);
        if (lane >= off) scan += v;
    }
    const float total = __shfl(scan, 63);
    const float c_hi_raw = fminf(scan * __builtin_amdgcn_rcpf(total), 1.0f); // cdf[lane+1]
    float c_lo = __shfl_up(c_hi_raw, 1);                                     // cdf[lane]
    if (lane == 0) c_lo = 0.0f;
    const float c_hi = c_hi_raw;

    // ---- interval-owner scatter of the 129 fine bin edges ----
    // lane k owns u in [cdf[k], cdf[k+1]); u_j = (j+0.5)/129.
    // j_start = ceil(129*c_lo - 0.5); adjacent lanes compute ceil of the
    // bitwise-identical cdf value -> exact partition of j in [0,129).
    {
        const float b_lo = near + range * ((float)lane * (1.0f / kT0));
        const float b_hi = near + range * ((float)(lane + 1) * (1.0f / kT0));
        const float bw = b_hi - b_lo;
        int j_start = (int)ceilf(fmaf(129.0f, c_lo, -0.5f));
        int j_end   = (int)ceilf(fmaf(129.0f, c_hi, -0.5f));
        j_start = j_start < 0 ? 0 : j_start;
        j_end   = j_end > (kTF + 1) ? (kTF + 1) : j_end;
        const float rdenom = __builtin_amdgcn_rcpf(c_hi - c_lo);
        for (int j = j_start; j < j_end; ++j) {
            const float u = ((float)j + 0.5f) * (1.0f / 129.0f);
            float t = (u - c_lo) * rdenom;
            t = fminf(fmaxf(t, 0.0f), 1.0f);
            s_zedge[wid][j] = fmaf(t, bw, b_lo);
        }
    }
    __syncthreads();

    // ---- per-lane: fine samples 2*lane and 2*lane+1 ----
    const float ze0 = s_zedge[wid][2 * lane + 0];
    const float ze1 = s_zedge[wid][2 * lane + 1];
    const float ze2 = s_zedge[wid][2 * lane + 2];
    const float d0 = ze1 - ze0, d1 = ze2 - ze1;
    const float z0 = 0.5f * (ze0 + ze1), z1 = 0.5f * (ze1 + ze2);

    const float2 sg = *(const float2*)(sigmas + (size_t)ray * kTF + 2 * lane);
    const float e0 = __expf(-sg.x * d0);
    const float e1 = __expf(-sg.y * d1);
    const float a0 = 1.0f - e0, a1 = 1.0f - e1;
    const float f0 = (1.0f - a0) + 1e-10f;
    const float f1 = (1.0f - a1) + 1e-10f;

    // ---- transmittance: in-wave exclusive product scan over 128 samples ----
    float p = f0 * f1;
    #pragma unroll
    for (int off = 1; off < 64; off <<= 1) {
        float v = __shfl_up(p, off);
        if (lane >= off) p *= v;
    }
    float excl = __shfl_up(p, 1);
    if (lane == 0) excl = 1.0f;
    const float tr0 = excl;
    const float tr1 = excl * f0;
    const float w0 = a0 * tr0;
    const float w1 = a1 * tr1;

    // ---- image/depth: in-wave reduction ----
    const float* rgb_row = rgbs + (size_t)ray * (kTF * 3) + 6 * lane;
    float vr = w0 * rgb_row[0] + w1 * rgb_row[3];
    float vg = w0 * rgb_row[1] + w1 * rgb_row[4];
    float vb = w0 * rgb_row[2] + w1 * rgb_row[5];
    float vd = w0 * z0 + w1 * z1;
    #pragma unroll
    for (int off = 32; off >= 1; off >>= 1) {
        vr += __shfl_down(vr, off);
        vg += __shfl_down(vg, off);
        vb += __shfl_down(vb, off);
        vd += __shfl_down(vd, off);
    }

    float* orow = out + (size_t)ray * (4 + kTF * 3);
    if (lane == 0) {
        orow[0] = vr; orow[1] = vg; orow[2] = vb; orow[3] = vd;
    }

    // ---- contraction + direct coalesced store (6 consecutive floats/lane) ----
    #pragma unroll
    for (int s = 0; s < 2; ++s) {
        const float z = s ? z1 : z0;
        float px = ox  + dx  * z;
        float py = oy  + dy  * z;
        float pz = ozr + dzr * z;
        const float ax = fabsf(px), ay = fabsf(py), az = fabsf(pz);
        float mag; int idx;
        if (ax >= ay && ax >= az) { mag = ax; idx = 0; }
        else if (ay >= az)        { mag = ay; idx = 1; }
        else                      { mag = az; idx = 2; }
        if (mag >= 1.0f) {
            const float inv  = __builtin_amdgcn_rcpf(mag);
            const float smax = (2.0f - inv) * inv;
            px *= (idx == 0) ? smax : inv;
            py *= (idx == 1) ? smax : inv;
            pz *= (idx == 2) ? smax : inv;
        }
        float* o = orow + 4 + 6 * lane + 3 * s;
        o[0] = px; o[1] = py; o[2] = pz;
    }
}

extern "C" void kernel_launch(void* const* d_in, const int* in_sizes, int n_in,
                              void* d_out, int out_size, void* d_ws, size_t ws_size,
                              hipStream_t stream) {
    const float* rays_o  = (const float*)d_in[0];
    const float* rays_d  = (const float*)d_in[1];
    const float* aabb    = (const float*)d_in[2];
    const float* weights = (const float*)d_in[3];
    const float* sigmas  = (const float*)d_in[4];
    const float* rgbs    = (const float*)d_in[5];
    float* out           = (float*)d_out;

    const int N = in_sizes[0] / 3;   // rays_o is [N,3]
    const int blocks = N / kRaysPerBlock;
    nerf_render_kernel<<<blocks, 256, 0, stream>>>(rays_o, rays_d, aabb, weights, sigmas, rgbs, out);
}

// Round 4
// 221.924 us; speedup vs baseline: 1.1592x; 1.0013x over previous
//
#include <hip/hip_runtime.h>

// One WAVE (64 lanes) per ray; 256-thread block = 4 fully-independent rays
// (no __syncthreads — s_zedge is per-wave, ordered by wave-local lgkmcnt).
// T0=64 coarse intervals, TF=128 fine samples; 2 fine samples per lane.
// Output row per ray: [image.rgb (3), depth (1), contracted xyz (3*TF)] = 388 f32.
//
// R3 was latency-bound (VALUBusy 40%, HBM 30%, both idle). R4:
//  - prefetch sigmas+rgbs at entry (in flight across the scans; vmcnt in-order
//    so consuming weights first keeps the 24B/lane rgb stream outstanding)
//  - drop the block barrier (waves decoupled)
//  - dwordx2/x4 global access, padded LDS rows for ds_read_b64

constexpr int kT0 = 64;
constexpr int kTF = 128;
constexpr int kRaysPerBlock = 4;   // 4 waves/block

__global__ __launch_bounds__(256)
void nerf_render_kernel(const float* __restrict__ rays_o,
                        const float* __restrict__ rays_d,
                        const float* __restrict__ aabb,
                        const float* __restrict__ weights,   // [N, 64]
                        const float* __restrict__ sigmas,    // [N, 128]
                        const float* __restrict__ rgbs,      // [N, 128, 3]
                        float* __restrict__ out)             // [N, 388]
{
    const int lane = threadIdx.x & 63;
    const int wid  = threadIdx.x >> 6;
    const int ray  = blockIdx.x * kRaysPerBlock + wid;

    __shared__ float s_zedge[kRaysPerBlock][kTF + 2];   // rows padded to 130 -> 8B-aligned

    // ---- issue ALL global streams up front (consume order: weights, sigma, rgb) ----
    const float wraw = weights[(size_t)ray * kT0 + lane];
    const float2 sg  = *(const float2*)(sigmas + (size_t)ray * kTF + 2 * lane);
    const float* rgb_row = rgbs + (size_t)ray * (kTF * 3) + 6 * lane;  // 8B-aligned
    const float2 rgA = *(const float2*)(rgb_row + 0);   // r0 g0
    const float2 rgB = *(const float2*)(rgb_row + 2);   // b0 r1
    const float2 rgC = *(const float2*)(rgb_row + 4);   // g1 b1

    // ---- ray-AABB near/far (wave-uniform -> scalar pipe; overlaps weights load) ----
    const float ox = rays_o[ray * 3 + 0], oy = rays_o[ray * 3 + 1], ozr = rays_o[ray * 3 + 2];
    const float dx = rays_d[ray * 3 + 0], dy = rays_d[ray * 3 + 1], dzr = rays_d[ray * 3 + 2];
    float near, far;
    {
        const float rx = __builtin_amdgcn_rcpf(dx + 1e-15f);
        const float ry = __builtin_amdgcn_rcpf(dy + 1e-15f);
        const float rz = __builtin_amdgcn_rcpf(dzr + 1e-15f);
        const float t0x = (aabb[0] - ox) * rx, t1x = (aabb[3] - ox) * rx;
        const float t0y = (aabb[1] - oy) * ry, t1y = (aabb[4] - oy) * ry;
        const float t0z = (aabb[2] - ozr) * rz, t1z = (aabb[5] - ozr) * rz;
        near = fmaxf(fmaxf(fminf(t0x, t1x), fminf(t0y, t1y)), fminf(t0z, t1z));
        far  = fminf(fminf(fmaxf(t0x, t1x), fmaxf(t0y, t1y)), fmaxf(t0z, t1z));
        if (far < near) { near = 1e9f; far = 1e9f; }
        near = fmaxf(near, 0.05f);
    }
    const float range = far - near;

    // ---- CDF inclusive scan over coarse weights ----
    float scan = wraw + 0.01f;
    #pragma unroll
    for (int off = 1; off < 64; off <<= 1) {
        float v = __shfl_up(scan, off);
        if (lane >= off) scan += v;
    }
    const float total = __shfl(scan, 63);
    const float c_hi = fminf(scan * __builtin_amdgcn_rcpf(total), 1.0f); // cdf[lane+1]
    float c_lo = __shfl_up(c_hi, 1);                                     // cdf[lane]
    if (lane == 0) c_lo = 0.0f;

    // ---- interval-owner scatter of the 129 fine bin edges ----
    // lane k owns u in [cdf[k], cdf[k+1]); u_j = (j+0.5)/129.
    // Adjacent lanes compute ceil of the bitwise-identical cdf value
    // -> exact partition of j in [0,129).
    {
        const float b_lo = near + range * ((float)lane * (1.0f / kT0));
        const float bw = range * (1.0f / kT0);
        int j_start = (int)ceilf(fmaf(129.0f, c_lo, -0.5f));
        int j_end   = (int)ceilf(fmaf(129.0f, c_hi, -0.5f));
        j_start = j_start < 0 ? 0 : j_start;
        j_end   = j_end > (kTF + 1) ? (kTF + 1) : j_end;
        const float rdenom = __builtin_amdgcn_rcpf(c_hi - c_lo);
        for (int j = j_start; j < j_end; ++j) {
            const float u = ((float)j + 0.5f) * (1.0f / 129.0f);
            float t = (u - c_lo) * rdenom;
            t = fminf(fmaxf(t, 0.0f), 1.0f);
            s_zedge[wid][j] = fmaf(t, bw, b_lo);
        }
    }
    // wave-local LDS ordering: all of this wave's ds_writes drained before reads.
    // (s_zedge[wid] is touched by this wave only -> no block barrier needed.)
    __builtin_amdgcn_wave_barrier();
    __asm__ volatile("s_waitcnt lgkmcnt(0)" ::: "memory");
    __builtin_amdgcn_wave_barrier();

    // ---- per-lane: fine samples 2*lane and 2*lane+1 ----
    const float2 ze01 = *(const float2*)&s_zedge[wid][2 * lane];  // 8B-aligned (row=130)
    const float  ze2  = s_zedge[wid][2 * lane + 2];
    const float d0 = ze01.y - ze01.x, d1 = ze2 - ze01.y;
    const float z0 = 0.5f * (ze01.x + ze01.y), z1 = 0.5f * (ze01.y + ze2);

    const float e0 = __expf(-sg.x * d0);
    const float e1 = __expf(-sg.y * d1);
    const float a0 = 1.0f - e0, a1 = 1.0f - e1;
    const float f0 = e0 + 1e-10f;
    const float f1 = e1 + 1e-10f;

    // ---- transmittance: in-wave exclusive product scan over 128 samples ----
    float p = f0 * f1;
    #pragma unroll
    for (int off = 1; off < 64; off <<= 1) {
        float v = __shfl_up(p, off);
        if (lane >= off) p *= v;
    }
    float excl = __shfl_up(p, 1);
    if (lane == 0) excl = 1.0f;
    const float w0 = a0 * excl;
    const float w1 = a1 * excl * f0;

    // ---- image/depth: in-wave reduction (4 interleaved chains) ----
    float vr = w0 * rgA.x + w1 * rgB.y;
    float vg = w0 * rgA.y + w1 * rgC.x;
    float vb = w0 * rgB.x + w1 * rgC.y;
    float vd = w0 * z0 + w1 * z1;
    #pragma unroll
    for (int off = 32; off >= 1; off >>= 1) {
        vr += __shfl_down(vr, off);
        vg += __shfl_down(vg, off);
        vb += __shfl_down(vb, off);
        vd += __shfl_down(vd, off);
    }

    float* orow = out + (size_t)ray * (4 + kTF * 3);   // 16B-aligned (388*4=1552)
    if (lane == 0) {
        *(float4*)orow = make_float4(vr, vg, vb, vd);
    }

    // ---- contraction (branchless) + dwordx2 stores (6 consecutive floats/lane) ----
    float oxyz[6];
    #pragma unroll
    for (int s = 0; s < 2; ++s) {
        const float z = s ? z1 : z0;
        float px = ox  + dx  * z;
        float py = oy  + dy  * z;
        float pz = ozr + dzr * z;
        const float ax = fabsf(px), ay = fabsf(py), az = fabsf(pz);
        float mag; int idx;
        if (ax >= ay && ax >= az) { mag = ax; idx = 0; }
        else if (ay >= az)        { mag = ay; idx = 1; }
        else                      { mag = az; idx = 2; }
        const float inv    = __builtin_amdgcn_rcpf(mag);
        const bool  inside = mag < 1.0f;
        const float s_oth  = inside ? 1.0f : inv;
        const float s_max  = inside ? 1.0f : (2.0f - inv) * inv;
        oxyz[3 * s + 0] = px * ((idx == 0) ? s_max : s_oth);
        oxyz[3 * s + 1] = py * ((idx == 1) ? s_max : s_oth);
        oxyz[3 * s + 2] = pz * ((idx == 2) ? s_max : s_oth);
    }
    float* o = orow + 4 + 6 * lane;                    // 8B-aligned
    *(float2*)(o + 0) = make_float2(oxyz[0], oxyz[1]);
    *(float2*)(o + 2) = make_float2(oxyz[2], oxyz[3]);
    *(float2*)(o + 4) = make_float2(oxyz[4], oxyz[5]);
}

extern "C" void kernel_launch(void* const* d_in, const int* in_sizes, int n_in,
                              void* d_out, int out_size, void* d_ws, size_t ws_size,
                              hipStream_t stream) {
    const float* rays_o  = (const float*)d_in[0];
    const float* rays_d  = (const float*)d_in[1];
    const float* aabb    = (const float*)d_in[2];
    const float* weights = (const float*)d_in[3];
    const float* sigmas  = (const float*)d_in[4];
    const float* rgbs    = (const float*)d_in[5];
    float* out           = (float*)d_out;

    const int N = in_sizes[0] / 3;   // rays_o is [N,3]
    const int blocks = N / kRaysPerBlock;
    nerf_render_kernel<<<blocks, 256, 0, stream>>>(rays_o, rays_d, aabb, weights, sigmas, rgbs, out);
}